// Round 19
// baseline (164.024 us; speedup 1.0000x reference)
//
#include <hip/hip_runtime.h>
#include <hip/hip_bf16.h>
#include <cstdint>
#include <cstddef>

using bf16 = __hip_bfloat16;
using short8 = __attribute__((ext_vector_type(8))) short;
using f32x4  = __attribute__((ext_vector_type(4))) float;
using f32x16 = __attribute__((ext_vector_type(16))) float;

#define DEVI __device__ __forceinline__

// async global->LDS, 16B per lane. LDS dest is wave-uniform base + lane*16.
DEVI void async_ld16(const void* g, void* l) {
  __builtin_amdgcn_global_load_lds(
      (const __attribute__((address_space(1))) unsigned int*)g,
      (__attribute__((address_space(3))) unsigned int*)l, 16, 0, 0);
}

DEVI unsigned int cvt_pk_bf16(float lo, float hi) {
  unsigned int r;
  asm("v_cvt_pk_bf16_f32 %0, %1, %2" : "=v"(r) : "v"(lo), "v"(hi));
  return r;
}

// ---------- fused prep: x->bf16 cvt | wq/wk/wv transpose | wo transpose | rope table
__global__ __launch_bounds__(256) void prep(
    const float* __restrict__ x, const float* __restrict__ wq,
    const float* __restrict__ wk, const float* __restrict__ wv,
    const float* __restrict__ wo, bf16* __restrict__ xb,
    bf16* __restrict__ wt, bf16* __restrict__ wot, float2* __restrict__ tab) {
  const int z = blockIdx.x, tid = threadIdx.x;
  if (z < 4096) {
    int i = z * 256 + tid;
    float4 v = ((const float4*)x)[i];
    union { bf16 h[4]; ushort4 u; } o;
    o.h[0] = __float2bfloat16(v.x);
    o.h[1] = __float2bfloat16(v.y);
    o.h[2] = __float2bfloat16(v.z);
    o.h[3] = __float2bfloat16(v.w);
    ((ushort4*)xb)[i] = o.u;
  } else if (z < 10240) {
    __shared__ float tile[32][33];
    const float* src; bf16* dst; int N, K, n0, k0, roff;
    if (z < 8192) {
      int z2 = z - 4096;
      int xb_ = z2 & 31, yb = (z2 >> 5) & 31, zz = z2 >> 10;
      if (zz < 2)       { src = wq; N = 2048; n0 = zz * 1024 + xb_ * 32; roff = zz * 1024 + xb_ * 32; }
      else if (zz == 2) { src = wk; N = 1024; n0 = xb_ * 32; roff = 2048 + xb_ * 32; }
      else              { src = wv; N = 1024; n0 = xb_ * 32; roff = 3072 + xb_ * 32; }
      K = 1024; k0 = yb * 32; dst = wt;
    } else {
      int z3 = z - 8192;
      int xb_ = z3 & 31, yb = z3 >> 5;
      src = wo; N = 1024; K = 2048; n0 = xb_ * 32; k0 = yb * 32; roff = xb_ * 32;
      dst = wot;
    }
    int tx = tid & 31, ty = tid >> 5;
#pragma unroll
    for (int i = 0; i < 32; i += 8)
      tile[ty + i][tx] = src[(size_t)(k0 + ty + i) * N + n0 + tx];
    __syncthreads();
#pragma unroll
    for (int i = 0; i < 32; i += 8)
      dst[(size_t)(roff + ty + i) * K + k0 + tx] = __float2bfloat16(tile[tx][ty + i]);
  } else {
    int z4 = z - 10240;
    int t = z4 * 4 + (tid >> 6), i = tid & 63;
    float ex = -2.f * (float)i * (1.f / 128.f);
    float theta = exp2f(ex * 19.9315685693241741f);  // log2(1e6)
    float f = (float)t * theta;
    float sv, cv;
    sincosf(f, &sv, &cv);
    tab[t * 64 + i] = make_float2(cv, sv);
  }
}

// ------- fused QKV GEMM v3: 128x128 tile, BK=32, DEPTH-4 counted vmcnt(12),
// 64KB LDS -> 2 blocks/CU, XCD n-stripe remap (each XCD owns 4 n-blocks => B L2-resident).
// Epilogues identical to R13: n_blk<16 Q (RMSNorm+RoPE+scale), 16..23 K, 24..31 V-transpose.
__global__ __launch_bounds__(256, 2) void gemm_qkv32d4(
    const bf16* __restrict__ A, const bf16* __restrict__ Bt,
    const float* __restrict__ qnw, const float* __restrict__ knw,
    const float2* __restrict__ tab,
    bf16* __restrict__ Qh, bf16* __restrict__ Kh, bf16* __restrict__ Vt) {
  __shared__ alignas(16) char SMEM[65536];   // A bufs [0,32K) 4x8KB, B bufs [32K,64K)
  const int tid = threadIdx.x, lane = tid & 63, w = tid >> 6;
  const int wm = w >> 1, wn = w & 1;
  // XCD stripe: xcd owns n-blocks [4*xcd, 4*xcd+4); within stripe m varies fastest
  const int bid = blockIdx.x;
  const int r_ = bid >> 3;
  const int bx = (bid & 7) * 4 + (r_ >> 5);      // n-block 0..31
  const int m0 = (r_ & 31) * 128, n0 = bx * 128;
  const int K = 1024, nt = 32;
  f32x4 acc[4][4] = {};

  // stage one BK=32 tile (A+B): 4 loads/thread. Pair-packed swizzle [R17-verified]:
  // granule c: pi=c>>3, s=(c&7)^(pi&7), row=2*pi+(s>>2), slot=s&3
  auto stage = [&](int buf, int kt) {
#pragma unroll
    for (int i = 0; i < 2; i++) {
      int c = tid + i * 256;
      int pi = c >> 3;
      int s  = (c & 7) ^ (pi & 7);
      int row = pi * 2 + (s >> 2);
      int sb  = (s & 3) * 16;
      async_ld16((const char*)(A  + (size_t)(m0 + row) * K + kt * 32) + sb,
                 SMEM + buf * 8192 + c * 16);
      async_ld16((const char*)(Bt + (size_t)(n0 + row) * K + kt * 32) + sb,
                 SMEM + 32768 + buf * 8192 + c * 16);
    }
  };

  stage(0, 0);
  stage(1, 1);
  stage(2, 2);
  stage(3, 3);

  for (int kt = 0; kt < nt; ++kt) {
    const int buf = kt & 3;
    if (kt + 4 <= nt)      asm volatile("s_waitcnt vmcnt(12)" ::: "memory");
    else if (kt + 3 == nt) asm volatile("s_waitcnt vmcnt(8)"  ::: "memory");
    else if (kt + 2 == nt) asm volatile("s_waitcnt vmcnt(4)"  ::: "memory");
    else                   asm volatile("s_waitcnt vmcnt(0)"  ::: "memory");
    __builtin_amdgcn_s_barrier();

    const char* Ab = SMEM + buf * 8192;
    const char* Bb = SMEM + 32768 + buf * 8192;
    short8 af[4], bfr[4];
#pragma unroll
    for (int mi = 0; mi < 4; mi++) {
      int r = wm * 64 + mi * 16 + (lane & 15);
      int pi = r >> 1;
      int sl = (((r & 1) << 2) + (lane >> 4)) ^ (pi & 7);
      af[mi] = *(const short8*)(Ab + pi * 128 + sl * 16);
    }
#pragma unroll
    for (int ni = 0; ni < 4; ni++) {
      int r = wn * 64 + ni * 16 + (lane & 15);
      int pi = r >> 1;
      int sl = (((r & 1) << 2) + (lane >> 4)) ^ (pi & 7);
      bfr[ni] = *(const short8*)(Bb + pi * 128 + sl * 16);
    }
#pragma unroll
    for (int mi = 0; mi < 4; mi++)
#pragma unroll
      for (int ni = 0; ni < 4; ni++)
        acc[mi][ni] = __builtin_amdgcn_mfma_f32_16x16x32_bf16(af[mi], bfr[ni], acc[mi][ni], 0, 0, 0);

    __builtin_amdgcn_s_barrier();
    __builtin_amdgcn_sched_barrier(0);
    if (kt + 4 < nt) stage(buf, kt + 4);
  }

  const int b = m0 >> 11;

  if (bx < 24) {
    // ---------- Q/K epilogue: RMSNorm + RoPE, head-major write [R13-proven]
    __syncthreads();
    float* ssb = (float*)SMEM;
    float s[4][4];
#pragma unroll
    for (int mi = 0; mi < 4; mi++)
#pragma unroll
      for (int r = 0; r < 4; r++) {
        float v0 = acc[mi][0][r], v1 = acc[mi][1][r];
        float v2 = acc[mi][2][r], v3 = acc[mi][3][r];
        float t = v0 * v0 + v1 * v1 + v2 * v2 + v3 * v3;
        t += __shfl_xor(t, 1);
        t += __shfl_xor(t, 2);
        t += __shfl_xor(t, 4);
        t += __shfl_xor(t, 8);
        s[mi][r] = t;
      }
    if ((lane & 15) == 0) {
#pragma unroll
      for (int mi = 0; mi < 4; mi++)
#pragma unroll
        for (int r = 0; r < 4; r++)
          ssb[wn * 128 + wm * 64 + mi * 16 + (lane >> 4) * 4 + r] = s[mi][r];
    }
    __syncthreads();

    const int isQ = (bx < 16);
    const int h = isQ ? bx : bx - 16;
    const float* wnp = isQ ? qnw : knw;
    bf16* dst = isQ ? Qh : Kh;
    const int NHH = isQ ? 16 : 8;
    const float qs = isQ ? 0.12751744416163417f : 1.f;  // fold softmax*log2e into Q
    float wd[4];
#pragma unroll
    for (int ni = 0; ni < 4; ni++) wd[ni] = wnp[wn * 64 + ni * 16 + (lane & 15)];

#pragma unroll
    for (int mi = 0; mi < 4; mi++)
#pragma unroll
      for (int r = 0; r < 4; r++) {
        int rl = wm * 64 + mi * 16 + (lane >> 4) * 4 + r;
        float tot = ssb[rl] + ssb[128 + rl];
        float inv = qs / (sqrtf(tot * 0.0078125f) + 1e-6f);
        int t = (m0 + rl) & 2047;
        bf16* drow = dst + ((size_t)(b * NHH + h) * 2048 + t) * 128;
#pragma unroll
        for (int ni = 0; ni < 4; ni++) {
          int d = wn * 64 + ni * 16 + (lane & 15);
          float val = acc[mi][ni][r] * inv * wd[ni];
          float prt = __shfl_xor(val, 1);
          float2 cs = tab[t * 64 + (d >> 1)];
          float o = (d & 1) ? (prt * cs.y + val * cs.x)
                            : (val * cs.x - prt * cs.y);
          drow[d] = __float2bfloat16(o);
        }
      }
  } else {
    // ---------- V epilogue: transpose 128x128 tile via LDS -> Vt[b*8+vh][d][t]
    __syncthreads();
    bf16* vt = (bf16*)SMEM;              // [128 d][128 t] rows 256B, XOR-swizzled (32KB)
    const int vh = bx - 24;
#pragma unroll
    for (int mi = 0; mi < 4; mi++)
#pragma unroll
      for (int ni = 0; ni < 4; ni++) {
        int d = wn * 64 + ni * 16 + (lane & 15);
        int tl = wm * 64 + mi * 16 + (lane >> 4) * 4;
        unsigned int p0 = cvt_pk_bf16(acc[mi][ni][0], acc[mi][ni][1]);
        unsigned int p1 = cvt_pk_bf16(acc[mi][ni][2], acc[mi][ni][3]);
        int byte = d * 256 + ((tl * 2) ^ ((d & 7) << 4));
        *(uint2*)((char*)vt + byte) = make_uint2(p0, p1);
      }
    __syncthreads();
    bf16* dstV = Vt + (size_t)(b * 8 + vh) * 128 * 2048 + (m0 & 2047);
#pragma unroll
    for (int i = 0; i < 8; i++) {
      int flat = tid + i * 256;
      int d = flat >> 4, g = flat & 15;
      short8 v = *(const short8*)((const char*)vt + d * 256 + ((g * 16) ^ ((d & 7) << 4)));
      *(short8*)(dstV + (size_t)d * 2048 + g * 8) = v;
    }
  }
}

// ------- out-proj GEMM, 64x128 tile, 2-deep counted vmcnt(6), 3 blocks/CU, f32 out
__global__ __launch_bounds__(256, 3) void gemm_out64(
    const bf16* __restrict__ A, const bf16* __restrict__ Bt,
    float* __restrict__ C, int M, int N, int K) {
  __shared__ alignas(16) bf16 As[2][64 * 64];
  __shared__ alignas(16) bf16 Bs[2][128 * 64];
  const int tid = threadIdx.x, lane = tid & 63, w = tid >> 6;
  const int m0 = blockIdx.y * 64, n0 = blockIdx.x * 128;
  const int nt = K >> 6;
  f32x4 acc[4][2] = {};

  auto stage = [&](int buf, int kt) {
#pragma unroll
    for (int i = 0; i < 2; i++) {
      int c = tid + i * 256;
      int row = c >> 3;
      int cb = ((c & 7) * 16) ^ ((row & 7) << 4);
      async_ld16((const char*)(A + (size_t)(m0 + row) * K + kt * 64) + cb,
                 (char*)As[buf] + i * 4096 + tid * 16);
    }
#pragma unroll
    for (int i = 0; i < 4; i++) {
      int c = tid + i * 256;
      int row = c >> 3;
      int cb = ((c & 7) * 16) ^ ((row & 7) << 4);
      async_ld16((const char*)(Bt + (size_t)(n0 + row) * K + kt * 64) + cb,
                 (char*)Bs[buf] + i * 4096 + tid * 16);
    }
  };

  stage(0, 0);
  stage(1, 1);

  for (int kt = 0; kt < nt; ++kt) {
    const int buf = kt & 1;
    if (kt + 1 < nt) asm volatile("s_waitcnt vmcnt(6)" ::: "memory");
    else             asm volatile("s_waitcnt vmcnt(0)" ::: "memory");
    __builtin_amdgcn_s_barrier();
#pragma unroll
    for (int ks = 0; ks < 2; ks++) {
      short8 af[4], bfr[2];
#pragma unroll
      for (int mi = 0; mi < 4; mi++) {
        int row = mi * 16 + (lane & 15);
        int cb = (ks * 64 + (lane >> 4) * 16) ^ ((row & 7) << 4);
        af[mi] = *(const short8*)((const char*)As[buf] + row * 128 + cb);
      }
#pragma unroll
      for (int ni = 0; ni < 2; ni++) {
        int row = w * 32 + ni * 16 + (lane & 15);
        int cb = (ks * 64 + (lane >> 4) * 16) ^ ((row & 7) << 4);
        bfr[ni] = *(const short8*)((const char*)Bs[buf] + row * 128 + cb);
      }
#pragma unroll
      for (int mi = 0; mi < 4; mi++)
#pragma unroll
        for (int ni = 0; ni < 2; ni++)
          acc[mi][ni] = __builtin_amdgcn_mfma_f32_16x16x32_bf16(af[mi], bfr[ni], acc[mi][ni], 0, 0, 0);
    }
    __builtin_amdgcn_s_barrier();
    __builtin_amdgcn_sched_barrier(0);
    if (kt + 2 < nt) stage(buf, kt + 2);
  }

  const int c0 = n0 + w * 32 + (lane & 15);
  const int r0 = m0 + (lane >> 4) * 4;
#pragma unroll
  for (int mi = 0; mi < 4; mi++)
#pragma unroll
    for (int ni = 0; ni < 2; ni++)
#pragma unroll
      for (int r = 0; r < 4; r++)
        C[(size_t)(r0 + mi * 16 + r) * N + (c0 + ni * 16)] = acc[mi][ni][r];
}

// -------- flash attention v10: in-block kv-split (2 grp x 4 warps), Q pre-scaled.
__global__ __launch_bounds__(512, 1) void flash_attn10(
    const bf16* __restrict__ Qh, const bf16* __restrict__ Kh,
    const bf16* __restrict__ Vt, bf16* __restrict__ Y) {
  __shared__ alignas(16) bf16 KB[4][64 * 128];   // [buf=set*2+grp][key][hd] 256B rows swz
  __shared__ alignas(16) bf16 VB[4][128 * 64];   // [buf][hd][key] 128B rows swz
  __shared__ float MLs[128][2];
  const int tid = threadIdx.x, lane = tid & 63, w = tid >> 6;
  const int hi = lane >> 5, lq = lane & 31;
  const int grp = w >> 2, wl = w & 3;

  const int g = blockIdx.x;
  const int bh = (g & 7) * 4 + ((g >> 3) & 3);   // XCD-grouped bh
  const int p  = g >> 5;                         // 0..7
  const int b = bh >> 4, h = bh & 15, kvh = h >> 1;

  const bf16* Qg = Qh + (size_t)(b * 16 + h) * 2048 * 128;
  const bf16* Kg = Kh + (size_t)(b * 8 + kvh) * 2048 * 128;
  const bf16* Vg = Vt + (size_t)(b * 8 + kvh) * 128 * 2048;

  short8 qf[8];
  f32x16 oacc[4];
  float m, l;
  int qw = 0, qg = 0;

  auto stage2 = [&](int set, int k0e) {
#pragma unroll
    for (int gb = 0; gb < 2; gb++) {
      const int k0 = k0e + gb * 64;
      char* kb = (char*)KB[set * 2 + gb];
      char* vb = (char*)VB[set * 2 + gb];
#pragma unroll
      for (int i = 0; i < 2; i++) {
        int c = w * 2 + i;
        {
          int row = c * 4 + (lane >> 4);
          int cb = ((lane & 15) * 16) ^ ((row & 7) << 4);
          async_ld16((const char*)Kg + (size_t)(k0 + row) * 256 + cb, kb + c * 1024);
        }
        {
          int row = c * 8 + (lane >> 3);
          int cb = ((lane & 7) * 16) ^ ((row & 7) << 4);
          async_ld16((const char*)Vg + (size_t)row * 4096 + (size_t)k0 * 2 + cb, vb + c * 1024);
        }
      }
    }
  };

  auto setupTile = [&](int q0) {
    qw = q0 + wl * 32;
    qg = qw + lq;
#pragma unroll
    for (int dc = 0; dc < 8; dc++)
      qf[dc] = *(const short8*)(Qg + (size_t)qg * 128 + dc * 16 + hi * 8);
#pragma unroll
    for (int dc = 0; dc < 4; dc++)
#pragma unroll
      for (int r = 0; r < 16; r++) oacc[dc][r] = 0.f;
    m = -1e30f;
    l = 0.f;
  };

  auto computeStep = [&](int bufI, int k0) {
    f32x16 st[2] = {};
#pragma unroll
    for (int kc = 0; kc < 2; kc++) {
      int row = kc * 32 + lq;
      int swz = (row & 7) << 4;
      const char* kbase = (const char*)KB[bufI] + row * 256;
#pragma unroll
      for (int dc = 0; dc < 8; dc++) {
        short8 kf = *(const short8*)(kbase + ((dc * 32 + hi * 16) ^ swz));
        st[kc] = __builtin_amdgcn_mfma_f32_32x32x16_bf16(kf, qf[dc], st[kc], 0, 0, 0);
      }
    }
    const bool msk = (k0 + 63 > qw);
    if (msk) {
#pragma unroll
      for (int kc = 0; kc < 2; kc++)
#pragma unroll
        for (int rr = 0; rr < 16; rr++) {
          int kg = k0 + kc * 32 + (rr & 3) + 8 * (rr >> 2) + 4 * hi;
          if (kg > qg) st[kc][rr] = -1e30f;
        }
    }
    float mx[16];
#pragma unroll
    for (int rr = 0; rr < 16; rr++) mx[rr] = fmaxf(st[0][rr], st[1][rr]);
#pragma unroll
    for (int off = 8; off >= 1; off >>= 1)
#pragma unroll
      for (int rr = 0; rr < 8; rr++)
        if (rr < off) mx[rr] = fmaxf(mx[rr], mx[rr + off]);
    float pm = fmaxf(mx[0], __shfl_xor(mx[0], 32));
    if (__any(pm > m + 8.f)) {
      float mnew = fmaxf(m, pm);
      float alpha = exp2f(m - mnew);
      m = mnew;
      l *= alpha;
      float al[16];
#pragma unroll
      for (int rr = 0; rr < 16; rr++)
        al[rr] = __shfl(alpha, (rr & 3) + 8 * (rr >> 2) + 4 * hi);
#pragma unroll
      for (int dc = 0; dc < 4; dc++)
#pragma unroll
        for (int rr = 0; rr < 16; rr++) oacc[dc][rr] *= al[rr];
    }
#pragma unroll
    for (int kc = 0; kc < 2; kc++)
#pragma unroll
      for (int rr = 0; rr < 16; rr++) st[kc][rr] = exp2f(st[kc][rr] - m);
    float sm[16];
#pragma unroll
    for (int rr = 0; rr < 16; rr++) sm[rr] = st[0][rr] + st[1][rr];
#pragma unroll
    for (int off = 8; off >= 1; off >>= 1)
#pragma unroll
      for (int rr = 0; rr < 8; rr++)
        if (rr < off) sm[rr] += sm[rr + off];
    l += sm[0] + __shfl_xor(sm[0], 32);
    short8 af[4];
#pragma unroll
    for (int kc = 0; kc < 2; kc++)
#pragma unroll
      for (int sb = 0; sb < 2; sb++) {
        int base = sb * 8;
        unsigned int a01 = cvt_pk_bf16(st[kc][base + 0], st[kc][base + 1]);
        unsigned int a23 = cvt_pk_bf16(st[kc][base + 2], st[kc][base + 3]);
        unsigned int b01 = cvt_pk_bf16(st[kc][base + 4], st[kc][base + 5]);
        unsigned int b23 = cvt_pk_bf16(st[kc][base + 6], st[kc][base + 7]);
        unsigned int xa01 = (unsigned int)__shfl_xor((int)a01, 32);
        unsigned int xa23 = (unsigned int)__shfl_xor((int)a23, 32);
        unsigned int xb01 = (unsigned int)__shfl_xor((int)b01, 32);
        unsigned int xb23 = (unsigned int)__shfl_xor((int)b23, 32);
        union { unsigned int u[4]; short8 s; } f;
        f.u[0] = hi ? xb01 : a01;
        f.u[1] = hi ? xb23 : a23;
        f.u[2] = hi ? b01 : xa01;
        f.u[3] = hi ? b23 : xa23;
        af[kc * 2 + sb] = f.s;
      }
#pragma unroll
    for (int dc = 0; dc < 4; dc++) {
      int row = dc * 32 + lq;
      int swz = (row & 7) << 4;
      const char* vbase = (const char*)VB[bufI] + row * 128;
#pragma unroll
      for (int ks = 0; ks < 4; ks++) {
        short8 vf = *(const short8*)(vbase + ((ks * 32 + hi * 16) ^ swz));
        oacc[dc] = __builtin_amdgcn_mfma_f32_32x32x16_bf16(af[ks], vf, oacc[dc], 0, 0, 0);
      }
    }
  };

  auto runRounds = [&](int n) {
    const int R = n >> 1;
    for (int r = 0; r < R; ++r) {
      asm volatile("s_waitcnt vmcnt(0)" ::: "memory");
      __builtin_amdgcn_s_barrier();
      if (r + 1 < R) stage2((r + 1) & 1, (2 * r + 2) * 64);
      __builtin_amdgcn_sched_barrier(0);
      const int s = 2 * r + grp, k0 = s * 64;
      const int bufI = (r & 1) * 2 + grp;
      if (k0 < qw + 32) computeStep(bufI, k0);
    }
  };

  auto writePartials = [&]() {
    float* base = (wl < 2) ? (float*)KB[2] : (float*)VB[2];
#pragma unroll
    for (int dc = 0; dc < 4; dc++)
#pragma unroll
      for (int rr = 0; rr < 16; rr++) {
        int q = (wl & 1) * 32 + (rr & 3) + 8 * (rr >> 2) + 4 * hi;
        base[q * 128 + dc * 32 + lq] = oacc[dc][rr];
      }
    if (lane < 32) {
      MLs[wl * 32 + lane][0] = m;
      MLs[wl * 32 + lane][1] = l;
    }
  };

  auto mergeAndY = [&](int q0) {
    float m1 = MLs[wl * 32 + lq][0], l1 = MLs[wl * 32 + lq][1];
    float mN = fmaxf(m, m1);
    float e0 = exp2f(m - mN), e1 = exp2f(m1 - mN);
    float lT = l * e0 + l1 * e1;
    float inv = 1.f / lT;
    float e0r[16], e1r[16], ivr[16];
#pragma unroll
    for (int rr = 0; rr < 16; rr++) {
      int src = (rr & 3) + 8 * (rr >> 2) + 4 * hi;
      e0r[rr] = __shfl(e0, src);
      e1r[rr] = __shfl(e1, src);
      ivr[rr] = __shfl(inv, src);
    }
    const float* base = (wl < 2) ? (const float*)KB[2] : (const float*)VB[2];
#pragma unroll
    for (int dc = 0; dc < 4; dc++)
#pragma unroll
      for (int rr = 0; rr < 16; rr++) {
        int q = (wl & 1) * 32 + (rr & 3) + 8 * (rr >> 2) + 4 * hi;
        float o1 = base[q * 128 + dc * 32 + lq];
        float oT = oacc[dc][rr] * e0r[rr] + o1 * e1r[rr];
        int t = q0 + wl * 32 + (rr & 3) + 8 * (rr >> 2) + 4 * hi;
        Y[(size_t)(b * 2048 + t) * 2048 + h * 128 + dc * 32 + lq] =
            __float2bfloat16(oT * ivr[rr]);
      }
  };

  const int jA = 15 - p, jB = p;
  const int q0A = jA * 128, nA = 2 * jA + 2;
  const int q0B = jB * 128, nB = 2 * jB + 2;

  setupTile(q0A);
  stage2(0, 0);
  runRounds(nA);
  __syncthreads();
  stage2(0, 0);
  if (grp == 1) writePartials();
  __syncthreads();
  if (grp == 0) mergeAndY(q0A);
  setupTile(q0B);
  runRounds(nB);
  __syncthreads();
  if (grp == 1) writePartials();
  __syncthreads();
  if (grp == 0) mergeAndY(q0B);
}

// ---------------------------------------------------------------- launcher
extern "C" void kernel_launch(void* const* d_in, const int* in_sizes, int n_in,
                              void* d_out, int out_size, void* d_ws, size_t ws_size,
                              hipStream_t stream) {
  (void)in_sizes; (void)n_in; (void)out_size; (void)ws_size;
  const float* x   = (const float*)d_in[0];
  const float* wq  = (const float*)d_in[1];
  const float* wk  = (const float*)d_in[2];
  const float* wv  = (const float*)d_in[3];
  const float* wo  = (const float*)d_in[4];
  const float* qnw = (const float*)d_in[5];
  const float* knw = (const float*)d_in[6];
  float* out = (float*)d_out;
  char* ws = (char*)d_ws;
  const size_t MB = 1u << 20;
  bf16*   xb  = (bf16*)(ws + 0 * MB);    // [4096][1024]
  bf16*   wt  = (bf16*)(ws + 8 * MB);    // [4096][1024]  rows: wq^T | wk^T | wv^T
  bf16*   wot = (bf16*)(ws + 16 * MB);   // [1024][2048]
  float2* tab = (float2*)(ws + 52 * MB); // [2048][64]
  bf16*   Qh  = (bf16*)(ws + 53 * MB);   // [2][16][2048][128] (pre-scaled)
  bf16*   Kh  = (bf16*)(ws + 69 * MB);   // [2][8][2048][128]
  bf16*   Vtr = (bf16*)(ws + 77 * MB);   // [2][8][128][2048]  (V transposed)
  bf16*   Yb  = (bf16*)(ws + 85 * MB);   // [4096][2048]

  prep<<<10752, 256, 0, stream>>>(x, wq, wk, wv, wo, xb, wt, wot, tab);
  gemm_qkv32d4<<<1024, 256, 0, stream>>>(xb, wt, qnw, knw, tab, Qh, Kh, Vtr);
  flash_attn10<<<256, 512, 0, stream>>>(Qh, Kh, Vtr, Yb);
  gemm_out64<<<dim3(8, 64), 256, 0, stream>>>(Yb, wot, out, 4096, 1024, 2048);
}

// Round 20
// 155.907 us; speedup vs baseline: 1.0521x; 1.0521x over previous
//
#include <hip/hip_runtime.h>
#include <hip/hip_bf16.h>
#include <cstdint>
#include <cstddef>

using bf16 = __hip_bfloat16;
using short8 = __attribute__((ext_vector_type(8))) short;
using f32x4  = __attribute__((ext_vector_type(4))) float;
using f32x16 = __attribute__((ext_vector_type(16))) float;

#define DEVI __device__ __forceinline__

// async global->LDS, 16B per lane. LDS dest is wave-uniform base + lane*16.
DEVI void async_ld16(const void* g, void* l) {
  __builtin_amdgcn_global_load_lds(
      (const __attribute__((address_space(1))) unsigned int*)g,
      (__attribute__((address_space(3))) unsigned int*)l, 16, 0, 0);
}

DEVI unsigned int cvt_pk_bf16(float lo, float hi) {
  unsigned int r;
  asm("v_cvt_pk_bf16_f32 %0, %1, %2" : "=v"(r) : "v"(lo), "v"(hi));
  return r;
}

// ---------- fused prep: x->bf16 cvt | wq/wk/wv transpose | wo transpose | rope table
__global__ __launch_bounds__(256) void prep(
    const float* __restrict__ x, const float* __restrict__ wq,
    const float* __restrict__ wk, const float* __restrict__ wv,
    const float* __restrict__ wo, bf16* __restrict__ xb,
    bf16* __restrict__ wt, bf16* __restrict__ wot, float2* __restrict__ tab) {
  const int z = blockIdx.x, tid = threadIdx.x;
  if (z < 4096) {
    int i = z * 256 + tid;
    float4 v = ((const float4*)x)[i];
    union { bf16 h[4]; ushort4 u; } o;
    o.h[0] = __float2bfloat16(v.x);
    o.h[1] = __float2bfloat16(v.y);
    o.h[2] = __float2bfloat16(v.z);
    o.h[3] = __float2bfloat16(v.w);
    ((ushort4*)xb)[i] = o.u;
  } else if (z < 10240) {
    __shared__ float tile[32][33];
    const float* src; bf16* dst; int N, K, n0, k0, roff;
    if (z < 8192) {
      int z2 = z - 4096;
      int xb_ = z2 & 31, yb = (z2 >> 5) & 31, zz = z2 >> 10;
      if (zz < 2)       { src = wq; N = 2048; n0 = zz * 1024 + xb_ * 32; roff = zz * 1024 + xb_ * 32; }
      else if (zz == 2) { src = wk; N = 1024; n0 = xb_ * 32; roff = 2048 + xb_ * 32; }
      else              { src = wv; N = 1024; n0 = xb_ * 32; roff = 3072 + xb_ * 32; }
      K = 1024; k0 = yb * 32; dst = wt;
    } else {
      int z3 = z - 8192;
      int xb_ = z3 & 31, yb = z3 >> 5;
      src = wo; N = 1024; K = 2048; n0 = xb_ * 32; k0 = yb * 32; roff = xb_ * 32;
      dst = wot;
    }
    int tx = tid & 31, ty = tid >> 5;
#pragma unroll
    for (int i = 0; i < 32; i += 8)
      tile[ty + i][tx] = src[(size_t)(k0 + ty + i) * N + n0 + tx];
    __syncthreads();
#pragma unroll
    for (int i = 0; i < 32; i += 8)
      dst[(size_t)(roff + ty + i) * K + k0 + tx] = __float2bfloat16(tile[tx][ty + i]);
  } else {
    int z4 = z - 10240;
    int t = z4 * 4 + (tid >> 6), i = tid & 63;
    float ex = -2.f * (float)i * (1.f / 128.f);
    float theta = exp2f(ex * 19.9315685693241741f);  // log2(1e6)
    float f = (float)t * theta;
    float sv, cv;
    sincosf(f, &sv, &cv);
    tab[t * 64 + i] = make_float2(cv, sv);
  }
}

// ------- fused QKV GEMM (128x128, 2-deep counted vmcnt(8), 2 blocks/CU) with
// per-head epilogue: bx<16 Q (RMSNorm+RoPE+scale -> Qh), 16..23 K (RMSNorm+RoPE
// -> Kh), 24..31 V (LDS transpose -> Vt[d][t]).  [R13/R16 measured-best]
__global__ __launch_bounds__(256, 2) void gemm_qkv(
    const bf16* __restrict__ A, const bf16* __restrict__ Bt,
    const float* __restrict__ qnw, const float* __restrict__ knw,
    const float2* __restrict__ tab,
    bf16* __restrict__ Qh, bf16* __restrict__ Kh, bf16* __restrict__ Vt) {
  __shared__ alignas(16) bf16 As[2][128 * 64];
  __shared__ alignas(16) bf16 Bs[2][128 * 64];
  const int tid = threadIdx.x, lane = tid & 63, w = tid >> 6;
  const int wm = w >> 1, wn = w & 1;
  const int bx = blockIdx.x;
  const int m0 = blockIdx.y * 128, n0 = bx * 128;
  const int K = 1024, nt = 16;
  f32x4 acc[4][4] = {};

  const int srow = lane >> 3;
  const int scb  = (lane & 7) * 16;

  auto stage = [&](int buf, int kt) {
#pragma unroll
    for (int i = 0; i < 4; i++) {
      int row = w * 32 + i * 8 + srow;
      int src_cb = scb ^ ((row & 7) << 4);
      async_ld16((const char*)(A  + (size_t)(m0 + row) * K + kt * 64) + src_cb,
                 (char*)As[buf] + w * 4096 + i * 1024);
      async_ld16((const char*)(Bt + (size_t)(n0 + row) * K + kt * 64) + src_cb,
                 (char*)Bs[buf] + w * 4096 + i * 1024);
    }
  };

  stage(0, 0);
  stage(1, 1);

  for (int kt = 0; kt < nt; ++kt) {
    const int buf = kt & 1;
    if (kt + 1 < nt) asm volatile("s_waitcnt vmcnt(8)" ::: "memory");
    else             asm volatile("s_waitcnt vmcnt(0)" ::: "memory");
    __builtin_amdgcn_s_barrier();
#pragma unroll
    for (int ks = 0; ks < 2; ks++) {
      short8 af[4], bfr[4];
#pragma unroll
      for (int mi = 0; mi < 4; mi++) {
        int row = wm * 64 + mi * 16 + (lane & 15);
        int cb = (ks * 64 + (lane >> 4) * 16) ^ ((row & 7) << 4);
        af[mi] = *(const short8*)((const char*)As[buf] + row * 128 + cb);
      }
#pragma unroll
      for (int ni = 0; ni < 4; ni++) {
        int row = wn * 64 + ni * 16 + (lane & 15);
        int cb = (ks * 64 + (lane >> 4) * 16) ^ ((row & 7) << 4);
        bfr[ni] = *(const short8*)((const char*)Bs[buf] + row * 128 + cb);
      }
#pragma unroll
      for (int mi = 0; mi < 4; mi++)
#pragma unroll
        for (int ni = 0; ni < 4; ni++)
          acc[mi][ni] = __builtin_amdgcn_mfma_f32_16x16x32_bf16(af[mi], bfr[ni], acc[mi][ni], 0, 0, 0);
    }
    __builtin_amdgcn_s_barrier();
    __builtin_amdgcn_sched_barrier(0);
    if (kt + 2 < nt) stage(buf, kt + 2);
  }

  const int b = m0 >> 11;

  if (bx < 24) {
    __syncthreads();
    float* ssb = (float*)As;
    float s[4][4];
#pragma unroll
    for (int mi = 0; mi < 4; mi++)
#pragma unroll
      for (int r = 0; r < 4; r++) {
        float v0 = acc[mi][0][r], v1 = acc[mi][1][r];
        float v2 = acc[mi][2][r], v3 = acc[mi][3][r];
        float t = v0 * v0 + v1 * v1 + v2 * v2 + v3 * v3;
        t += __shfl_xor(t, 1);
        t += __shfl_xor(t, 2);
        t += __shfl_xor(t, 4);
        t += __shfl_xor(t, 8);
        s[mi][r] = t;
      }
    if ((lane & 15) == 0) {
#pragma unroll
      for (int mi = 0; mi < 4; mi++)
#pragma unroll
        for (int r = 0; r < 4; r++)
          ssb[wn * 128 + wm * 64 + mi * 16 + (lane >> 4) * 4 + r] = s[mi][r];
    }
    __syncthreads();

    const int isQ = (bx < 16);
    const int h = isQ ? bx : bx - 16;
    const float* wnp = isQ ? qnw : knw;
    bf16* dst = isQ ? Qh : Kh;
    const int NHH = isQ ? 16 : 8;
    const float qs = isQ ? 0.12751744416163417f : 1.f;
    float wd[4];
#pragma unroll
    for (int ni = 0; ni < 4; ni++) wd[ni] = wnp[wn * 64 + ni * 16 + (lane & 15)];

#pragma unroll
    for (int mi = 0; mi < 4; mi++)
#pragma unroll
      for (int r = 0; r < 4; r++) {
        int rl = wm * 64 + mi * 16 + (lane >> 4) * 4 + r;
        float tot = ssb[rl] + ssb[128 + rl];
        float inv = qs / (sqrtf(tot * 0.0078125f) + 1e-6f);
        int t = (m0 + rl) & 2047;
        bf16* drow = dst + ((size_t)(b * NHH + h) * 2048 + t) * 128;
#pragma unroll
        for (int ni = 0; ni < 4; ni++) {
          int d = wn * 64 + ni * 16 + (lane & 15);
          float val = acc[mi][ni][r] * inv * wd[ni];
          float prt = __shfl_xor(val, 1);
          float2 cs = tab[t * 64 + (d >> 1)];
          float o = (d & 1) ? (prt * cs.y + val * cs.x)
                            : (val * cs.x - prt * cs.y);
          drow[d] = __float2bfloat16(o);
        }
      }
  } else {
    __syncthreads();
    bf16* vt = (bf16*)As;                // [128 d][128 t] rows 256B, XOR-swizzled
    const int vh = bx - 24;
#pragma unroll
    for (int mi = 0; mi < 4; mi++)
#pragma unroll
      for (int ni = 0; ni < 4; ni++) {
        int d = wn * 64 + ni * 16 + (lane & 15);
        int tl = wm * 64 + mi * 16 + (lane >> 4) * 4;
        unsigned int p0 = cvt_pk_bf16(acc[mi][ni][0], acc[mi][ni][1]);
        unsigned int p1 = cvt_pk_bf16(acc[mi][ni][2], acc[mi][ni][3]);
        int byte = d * 256 + ((tl * 2) ^ ((d & 7) << 4));
        *(uint2*)((char*)vt + byte) = make_uint2(p0, p1);
      }
    __syncthreads();
    bf16* dstV = Vt + (size_t)(b * 8 + vh) * 128 * 2048 + (m0 & 2047);
#pragma unroll
    for (int i = 0; i < 8; i++) {
      int flat = tid + i * 256;
      int d = flat >> 4, g = flat & 15;
      short8 v = *(const short8*)((const char*)vt + d * 256 + ((g * 16) ^ ((d & 7) << 4)));
      *(short8*)(dstV + (size_t)d * 2048 + g * 8) = v;
    }
  }
}

// ------- out-proj GEMM, 64x128 tile, 2-deep counted vmcnt(6), 3 blocks/CU, f32 out
__global__ __launch_bounds__(256, 3) void gemm_out64(
    const bf16* __restrict__ A, const bf16* __restrict__ Bt,
    float* __restrict__ C, int M, int N, int K) {
  __shared__ alignas(16) bf16 As[2][64 * 64];
  __shared__ alignas(16) bf16 Bs[2][128 * 64];
  const int tid = threadIdx.x, lane = tid & 63, w = tid >> 6;
  const int m0 = blockIdx.y * 64, n0 = blockIdx.x * 128;
  const int nt = K >> 6;
  f32x4 acc[4][2] = {};

  auto stage = [&](int buf, int kt) {
#pragma unroll
    for (int i = 0; i < 2; i++) {
      int c = tid + i * 256;
      int row = c >> 3;
      int cb = ((c & 7) * 16) ^ ((row & 7) << 4);
      async_ld16((const char*)(A + (size_t)(m0 + row) * K + kt * 64) + cb,
                 (char*)As[buf] + i * 4096 + tid * 16);
    }
#pragma unroll
    for (int i = 0; i < 4; i++) {
      int c = tid + i * 256;
      int row = c >> 3;
      int cb = ((c & 7) * 16) ^ ((row & 7) << 4);
      async_ld16((const char*)(Bt + (size_t)(n0 + row) * K + kt * 64) + cb,
                 (char*)Bs[buf] + i * 4096 + tid * 16);
    }
  };

  stage(0, 0);
  stage(1, 1);

  for (int kt = 0; kt < nt; ++kt) {
    const int buf = kt & 1;
    if (kt + 1 < nt) asm volatile("s_waitcnt vmcnt(6)" ::: "memory");
    else             asm volatile("s_waitcnt vmcnt(0)" ::: "memory");
    __builtin_amdgcn_s_barrier();
#pragma unroll
    for (int ks = 0; ks < 2; ks++) {
      short8 af[4], bfr[2];
#pragma unroll
      for (int mi = 0; mi < 4; mi++) {
        int row = mi * 16 + (lane & 15);
        int cb = (ks * 64 + (lane >> 4) * 16) ^ ((row & 7) << 4);
        af[mi] = *(const short8*)((const char*)As[buf] + row * 128 + cb);
      }
#pragma unroll
      for (int ni = 0; ni < 2; ni++) {
        int row = w * 32 + ni * 16 + (lane & 15);
        int cb = (ks * 64 + (lane >> 4) * 16) ^ ((row & 7) << 4);
        bfr[ni] = *(const short8*)((const char*)Bs[buf] + row * 128 + cb);
      }
#pragma unroll
      for (int mi = 0; mi < 4; mi++)
#pragma unroll
        for (int ni = 0; ni < 2; ni++)
          acc[mi][ni] = __builtin_amdgcn_mfma_f32_16x16x32_bf16(af[mi], bfr[ni], acc[mi][ni], 0, 0, 0);
    }
    __builtin_amdgcn_s_barrier();
    __builtin_amdgcn_sched_barrier(0);
    if (kt + 2 < nt) stage(buf, kt + 2);
  }

  const int c0 = n0 + w * 32 + (lane & 15);
  const int r0 = m0 + (lane >> 4) * 4;
#pragma unroll
  for (int mi = 0; mi < 4; mi++)
#pragma unroll
    for (int ni = 0; ni < 2; ni++)
#pragma unroll
      for (int r = 0; r < 4; r++)
        C[(size_t)(r0 + mi * 16 + r) * N + (c0 + ni * 16)] = acc[mi][ni][r];
}

// -------- flash attention v10: in-block kv-split (2 grp x 4 warps), Q pre-scaled.
__global__ __launch_bounds__(512, 1) void flash_attn10(
    const bf16* __restrict__ Qh, const bf16* __restrict__ Kh,
    const bf16* __restrict__ Vt, bf16* __restrict__ Y) {
  __shared__ alignas(16) bf16 KB[4][64 * 128];   // [buf=set*2+grp][key][hd] 256B rows swz
  __shared__ alignas(16) bf16 VB[4][128 * 64];   // [buf][hd][key] 128B rows swz
  __shared__ float MLs[128][2];
  const int tid = threadIdx.x, lane = tid & 63, w = tid >> 6;
  const int hi = lane >> 5, lq = lane & 31;
  const int grp = w >> 2, wl = w & 3;

  const int g = blockIdx.x;
  const int bh = (g & 7) * 4 + ((g >> 3) & 3);   // XCD-grouped bh
  const int p  = g >> 5;                         // 0..7
  const int b = bh >> 4, h = bh & 15, kvh = h >> 1;

  const bf16* Qg = Qh + (size_t)(b * 16 + h) * 2048 * 128;
  const bf16* Kg = Kh + (size_t)(b * 8 + kvh) * 2048 * 128;
  const bf16* Vg = Vt + (size_t)(b * 8 + kvh) * 128 * 2048;

  short8 qf[8];
  f32x16 oacc[4];
  float m, l;
  int qw = 0, qg = 0;

  auto stage2 = [&](int set, int k0e) {
#pragma unroll
    for (int gb = 0; gb < 2; gb++) {
      const int k0 = k0e + gb * 64;
      char* kb = (char*)KB[set * 2 + gb];
      char* vb = (char*)VB[set * 2 + gb];
#pragma unroll
      for (int i = 0; i < 2; i++) {
        int c = w * 2 + i;
        {
          int row = c * 4 + (lane >> 4);
          int cb = ((lane & 15) * 16) ^ ((row & 7) << 4);
          async_ld16((const char*)Kg + (size_t)(k0 + row) * 256 + cb, kb + c * 1024);
        }
        {
          int row = c * 8 + (lane >> 3);
          int cb = ((lane & 7) * 16) ^ ((row & 7) << 4);
          async_ld16((const char*)Vg + (size_t)row * 4096 + (size_t)k0 * 2 + cb, vb + c * 1024);
        }
      }
    }
  };

  auto setupTile = [&](int q0) {
    qw = q0 + wl * 32;
    qg = qw + lq;
#pragma unroll
    for (int dc = 0; dc < 8; dc++)
      qf[dc] = *(const short8*)(Qg + (size_t)qg * 128 + dc * 16 + hi * 8);
#pragma unroll
    for (int dc = 0; dc < 4; dc++)
#pragma unroll
      for (int r = 0; r < 16; r++) oacc[dc][r] = 0.f;
    m = -1e30f;
    l = 0.f;
  };

  auto computeStep = [&](int bufI, int k0) {
    f32x16 st[2] = {};
#pragma unroll
    for (int kc = 0; kc < 2; kc++) {
      int row = kc * 32 + lq;
      int swz = (row & 7) << 4;
      const char* kbase = (const char*)KB[bufI] + row * 256;
#pragma unroll
      for (int dc = 0; dc < 8; dc++) {
        short8 kf = *(const short8*)(kbase + ((dc * 32 + hi * 16) ^ swz));
        st[kc] = __builtin_amdgcn_mfma_f32_32x32x16_bf16(kf, qf[dc], st[kc], 0, 0, 0);
      }
    }
    const bool msk = (k0 + 63 > qw);
    if (msk) {
#pragma unroll
      for (int kc = 0; kc < 2; kc++)
#pragma unroll
        for (int rr = 0; rr < 16; rr++) {
          int kg = k0 + kc * 32 + (rr & 3) + 8 * (rr >> 2) + 4 * hi;
          if (kg > qg) st[kc][rr] = -1e30f;
        }
    }
    float mx[16];
#pragma unroll
    for (int rr = 0; rr < 16; rr++) mx[rr] = fmaxf(st[0][rr], st[1][rr]);
#pragma unroll
    for (int off = 8; off >= 1; off >>= 1)
#pragma unroll
      for (int rr = 0; rr < 8; rr++)
        if (rr < off) mx[rr] = fmaxf(mx[rr], mx[rr + off]);
    float pm = fmaxf(mx[0], __shfl_xor(mx[0], 32));
    if (__any(pm > m + 8.f)) {
      float mnew = fmaxf(m, pm);
      float alpha = exp2f(m - mnew);
      m = mnew;
      l *= alpha;
      float al[16];
#pragma unroll
      for (int rr = 0; rr < 16; rr++)
        al[rr] = __shfl(alpha, (rr & 3) + 8 * (rr >> 2) + 4 * hi);
#pragma unroll
      for (int dc = 0; dc < 4; dc++)
#pragma unroll
        for (int rr = 0; rr < 16; rr++) oacc[dc][rr] *= al[rr];
    }
#pragma unroll
    for (int kc = 0; kc < 2; kc++)
#pragma unroll
      for (int rr = 0; rr < 16; rr++) st[kc][rr] = exp2f(st[kc][rr] - m);
    float sm[16];
#pragma unroll
    for (int rr = 0; rr < 16; rr++) sm[rr] = st[0][rr] + st[1][rr];
#pragma unroll
    for (int off = 8; off >= 1; off >>= 1)
#pragma unroll
      for (int rr = 0; rr < 8; rr++)
        if (rr < off) sm[rr] += sm[rr + off];
    l += sm[0] + __shfl_xor(sm[0], 32);
    short8 af[4];
#pragma unroll
    for (int kc = 0; kc < 2; kc++)
#pragma unroll
      for (int sb = 0; sb < 2; sb++) {
        int base = sb * 8;
        unsigned int a01 = cvt_pk_bf16(st[kc][base + 0], st[kc][base + 1]);
        unsigned int a23 = cvt_pk_bf16(st[kc][base + 2], st[kc][base + 3]);
        unsigned int b01 = cvt_pk_bf16(st[kc][base + 4], st[kc][base + 5]);
        unsigned int b23 = cvt_pk_bf16(st[kc][base + 6], st[kc][base + 7]);
        unsigned int xa01 = (unsigned int)__shfl_xor((int)a01, 32);
        unsigned int xa23 = (unsigned int)__shfl_xor((int)a23, 32);
        unsigned int xb01 = (unsigned int)__shfl_xor((int)b01, 32);
        unsigned int xb23 = (unsigned int)__shfl_xor((int)b23, 32);
        union { unsigned int u[4]; short8 s; } f;
        f.u[0] = hi ? xb01 : a01;
        f.u[1] = hi ? xb23 : a23;
        f.u[2] = hi ? b01 : xa01;
        f.u[3] = hi ? b23 : xa23;
        af[kc * 2 + sb] = f.s;
      }
#pragma unroll
    for (int dc = 0; dc < 4; dc++) {
      int row = dc * 32 + lq;
      int swz = (row & 7) << 4;
      const char* vbase = (const char*)VB[bufI] + row * 128;
#pragma unroll
      for (int ks = 0; ks < 4; ks++) {
        short8 vf = *(const short8*)(vbase + ((ks * 32 + hi * 16) ^ swz));
        oacc[dc] = __builtin_amdgcn_mfma_f32_32x32x16_bf16(af[ks], vf, oacc[dc], 0, 0, 0);
      }
    }
  };

  auto runRounds = [&](int n) {
    const int R = n >> 1;
    for (int r = 0; r < R; ++r) {
      asm volatile("s_waitcnt vmcnt(0)" ::: "memory");
      __builtin_amdgcn_s_barrier();
      if (r + 1 < R) stage2((r + 1) & 1, (2 * r + 2) * 64);
      __builtin_amdgcn_sched_barrier(0);
      const int s = 2 * r + grp, k0 = s * 64;
      const int bufI = (r & 1) * 2 + grp;
      if (k0 < qw + 32) computeStep(bufI, k0);
    }
  };

  auto writePartials = [&]() {
    float* base = (wl < 2) ? (float*)KB[2] : (float*)VB[2];
#pragma unroll
    for (int dc = 0; dc < 4; dc++)
#pragma unroll
      for (int rr = 0; rr < 16; rr++) {
        int q = (wl & 1) * 32 + (rr & 3) + 8 * (rr >> 2) + 4 * hi;
        base[q * 128 + dc * 32 + lq] = oacc[dc][rr];
      }
    if (lane < 32) {
      MLs[wl * 32 + lane][0] = m;
      MLs[wl * 32 + lane][1] = l;
    }
  };

  auto mergeAndY = [&](int q0) {
    float m1 = MLs[wl * 32 + lq][0], l1 = MLs[wl * 32 + lq][1];
    float mN = fmaxf(m, m1);
    float e0 = exp2f(m - mN), e1 = exp2f(m1 - mN);
    float lT = l * e0 + l1 * e1;
    float inv = 1.f / lT;
    float e0r[16], e1r[16], ivr[16];
#pragma unroll
    for (int rr = 0; rr < 16; rr++) {
      int src = (rr & 3) + 8 * (rr >> 2) + 4 * hi;
      e0r[rr] = __shfl(e0, src);
      e1r[rr] = __shfl(e1, src);
      ivr[rr] = __shfl(inv, src);
    }
    const float* base = (wl < 2) ? (const float*)KB[2] : (const float*)VB[2];
#pragma unroll
    for (int dc = 0; dc < 4; dc++)
#pragma unroll
      for (int rr = 0; rr < 16; rr++) {
        int q = (wl & 1) * 32 + (rr & 3) + 8 * (rr >> 2) + 4 * hi;
        float o1 = base[q * 128 + dc * 32 + lq];
        float oT = oacc[dc][rr] * e0r[rr] + o1 * e1r[rr];
        int t = q0 + wl * 32 + (rr & 3) + 8 * (rr >> 2) + 4 * hi;
        Y[(size_t)(b * 2048 + t) * 2048 + h * 128 + dc * 32 + lq] =
            __float2bfloat16(oT * ivr[rr]);
      }
  };

  const int jA = 15 - p, jB = p;
  const int q0A = jA * 128, nA = 2 * jA + 2;
  const int q0B = jB * 128, nB = 2 * jB + 2;

  setupTile(q0A);
  stage2(0, 0);
  runRounds(nA);
  __syncthreads();
  stage2(0, 0);
  if (grp == 1) writePartials();
  __syncthreads();
  if (grp == 0) mergeAndY(q0A);
  setupTile(q0B);
  runRounds(nB);
  __syncthreads();
  if (grp == 1) writePartials();
  __syncthreads();
  if (grp == 0) mergeAndY(q0B);
}

// ---------------------------------------------------------------- launcher
extern "C" void kernel_launch(void* const* d_in, const int* in_sizes, int n_in,
                              void* d_out, int out_size, void* d_ws, size_t ws_size,
                              hipStream_t stream) {
  (void)in_sizes; (void)n_in; (void)out_size; (void)ws_size;
  const float* x   = (const float*)d_in[0];
  const float* wq  = (const float*)d_in[1];
  const float* wk  = (const float*)d_in[2];
  const float* wv  = (const float*)d_in[3];
  const float* wo  = (const float*)d_in[4];
  const float* qnw = (const float*)d_in[5];
  const float* knw = (const float*)d_in[6];
  float* out = (float*)d_out;
  char* ws = (char*)d_ws;
  const size_t MB = 1u << 20;
  bf16*   xb  = (bf16*)(ws + 0 * MB);    // [4096][1024]
  bf16*   wt  = (bf16*)(ws + 8 * MB);    // [4096][1024]  rows: wq^T | wk^T | wv^T
  bf16*   wot = (bf16*)(ws + 16 * MB);   // [1024][2048]
  float2* tab = (float2*)(ws + 52 * MB); // [2048][64]
  bf16*   Qh  = (bf16*)(ws + 53 * MB);   // [2][16][2048][128] (pre-scaled)
  bf16*   Kh  = (bf16*)(ws + 69 * MB);   // [2][8][2048][128]
  bf16*   Vtr = (bf16*)(ws + 77 * MB);   // [2][8][128][2048]  (V transposed)
  bf16*   Yb  = (bf16*)(ws + 85 * MB);   // [4096][2048]

  prep<<<10752, 256, 0, stream>>>(x, wq, wk, wv, wo, xb, wt, wot, tab);
  gemm_qkv<<<dim3(32, 32), 256, 0, stream>>>(xb, wt, qnw, knw, tab, Qh, Kh, Vtr);
  flash_attn10<<<256, 512, 0, stream>>>(Qh, Kh, Vtr, Yb);
  gemm_out64<<<dim3(8, 64), 256, 0, stream>>>(Yb, wot, out, 4096, 1024, 2048);
}